// Round 2
// baseline (1800.078 us; speedup 1.0000x reference)
//
#include <hip/hip_runtime.h>
#include <hip/hip_bf16.h>
#include <math.h>

#define N_NODES 100000
#define E_EDGES 3200000
#define IN_DIM  256

typedef __attribute__((ext_vector_type(8))) short bf16x8;
typedef __attribute__((ext_vector_type(4))) float f32x4;
typedef __attribute__((ext_vector_type(2))) unsigned int uint2v;

// ---- bf16 helpers ---------------------------------------------------------
__device__ __forceinline__ unsigned short f2bf(float f) {
  unsigned u = __float_as_uint(f);
  u += 0x7fffu + ((u >> 16) & 1u);   // RTNE
  return (unsigned short)(u >> 16);
}
__device__ __forceinline__ float bf2f(unsigned short h) {
  return __uint_as_float(((unsigned)h) << 16);
}

// ---------------- BN column stats (sum, sumsq per feature) ----------------
__global__ __launch_bounds__(256) void bn_stats_kernel(
    const float* __restrict__ x, float* __restrict__ sums /*512 floats*/) {
  int c = threadIdx.x;
  float s = 0.f, s2 = 0.f;
  for (int r = blockIdx.x; r < N_NODES; r += gridDim.x) {
    float v = x[(size_t)r * IN_DIM + c];
    s += v; s2 += v * v;
  }
  atomicAdd(&sums[c], s);
  atomicAdd(&sums[256 + c], s2);
}

// ------------- fold BN affine into W_in / b_in ----------------------------
__global__ __launch_bounds__(256) void fold_bn_kernel(
    const float* __restrict__ sums, const float* __restrict__ bn_g,
    const float* __restrict__ bn_b, const float* __restrict__ W_in,
    const float* __restrict__ b_in, float* __restrict__ Wf,
    float* __restrict__ bf) {
  int j = blockIdx.x;   // out col 0..139
  int c = threadIdx.x;  // in col 0..255
  const float invN = 1.0f / (float)N_NODES;
  float mu  = sums[c] * invN;
  float var = sums[256 + c] * invN - mu * mu;
  float s   = bn_g[c] * rsqrtf(var + 1e-5f);
  float t   = bn_b[c] - mu * s;
  float w   = W_in[(size_t)c * 140 + j];
  Wf[(size_t)c * 140 + j] = s * w;
  float v = t * w;
  for (int o = 32; o > 0; o >>= 1) v += __shfl_down(v, o, 64);
  __shared__ float red[4];
  int wid = threadIdx.x >> 6, lane = threadIdx.x & 63;
  if (lane == 0) red[wid] = v;
  __syncthreads();
  if (threadIdx.x == 0)
    bf[j] = b_in[j] + red[0] + red[1] + red[2] + red[3];
}

// ---------------- CSR row_ptr from sorted rows (binary search) -------------
__global__ __launch_bounds__(256) void build_rowptr_kernel(
    const int* __restrict__ rows, int* __restrict__ rowptr) {
  int r = blockIdx.x * 256 + threadIdx.x;
  if (r > N_NODES) return;
  int lo = 0, hi = E_EDGES;
  while (lo < hi) {
    int mid = (lo + hi) >> 1;
    if (rows[mid] < r) lo = mid + 1; else hi = mid;
  }
  rowptr[r] = lo;
}

// ------- pack fp32 W[K,M] into MFMA B-fragment order, bf16, zero-padded ----
// Bp[(kt*NT + nt)*64 + lane] = uint4 of 8 bf16: B[kt*32+(lane>>4)*8+j][nt*16+(lane&15)]
__global__ __launch_bounds__(256) void pack_w_kernel(
    const float* __restrict__ W, uint4* __restrict__ Bp, int K, int M, int NT,
    int total) {
  int id = blockIdx.x * 256 + threadIdx.x;
  if (id >= total) return;
  int lane = id & 63;
  int nt = (id >> 6) % NT;
  int kt = id / (64 * NT);
  int n = nt * 16 + (lane & 15);
  int kbase = kt * 32 + (lane >> 4) * 8;
  unsigned short v[8];
#pragma unroll
  for (int j = 0; j < 8; ++j) {
    int k = kbase + j;
    v[j] = (k < K && n < M) ? f2bf(W[(size_t)k * M + n]) : (unsigned short)0;
  }
  Bp[id] = *(uint4*)v;
}

// ---------------- MFMA bf16 GEMM -------------------------------------------
// C[N, ldc] = act(A[N, KPAD] @ B[KPAD, NT*16] + bias); A fp32 or bf16.
// KPAD must be a multiple of 64. 256 thr = 4 waves; block tile 128 rows.
template <int KPAD, int NT, typename AT>
__global__ __launch_bounds__(256) void mfma_gemm_kernel(
    const AT* __restrict__ A, const uint4* __restrict__ Bp,
    const float* __restrict__ bias, void* __restrict__ C,
    int M, int Mstore, int ldc, int act, int outfmt) {
  static_assert(KPAD % 64 == 0, "KPAD must be a multiple of 64");
  __shared__ unsigned short As[128 * 72];  // 64-k chunk, stride 72 (2-way only)
  int tid = threadIdx.x;
  int lane = tid & 63;
  int wave = tid >> 6;
  int quad = lane >> 4, m16 = lane & 15;
  int rbase = blockIdx.x * 128;
  int wrow = wave * 32;

  f32x4 acc[2][NT];
#pragma unroll
  for (int mt = 0; mt < 2; ++mt)
#pragma unroll
    for (int nt = 0; nt < NT; ++nt)
      acc[mt][nt] = (f32x4){0.f, 0.f, 0.f, 0.f};

  for (int k0 = 0; k0 < KPAD; k0 += 64) {
    if constexpr (sizeof(AT) == 2) {
      int r0 = tid >> 3, q = tid & 7;
#pragma unroll
      for (int it = 0; it < 4; ++it) {
        int r = r0 + it * 32;
        int row = rbase + r;
        uint4 v = make_uint4(0u, 0u, 0u, 0u);
        if (row < N_NODES)
          v = *(const uint4*)((const unsigned short*)A + (size_t)row * KPAD + k0 + q * 8);
        *(uint4*)&As[r * 72 + q * 8] = v;
      }
    } else {
      int r0 = tid >> 4, fq = tid & 15;
#pragma unroll
      for (int it = 0; it < 8; ++it) {
        int r = r0 + it * 16;
        int row = rbase + r;
        float4 v = make_float4(0.f, 0.f, 0.f, 0.f);
        if (row < N_NODES)
          v = *(const float4*)((const float*)A + (size_t)row * KPAD + k0 + fq * 4);
        unsigned short p[4] = {f2bf(v.x), f2bf(v.y), f2bf(v.z), f2bf(v.w)};
        *(uint2*)&As[r * 72 + fq * 4] = *(uint2*)p;
      }
    }
    __syncthreads();
#pragma unroll
    for (int s = 0; s < 2; ++s) {
      int kt = (k0 >> 5) + s;
      bf16x8 a0 = *(const bf16x8*)&As[(wrow + m16) * 72 + s * 32 + quad * 8];
      bf16x8 a1 = *(const bf16x8*)&As[(wrow + 16 + m16) * 72 + s * 32 + quad * 8];
#pragma unroll
      for (int nt = 0; nt < NT; ++nt) {
        uint4 bw = Bp[(size_t)(kt * NT + nt) * 64 + lane];
        bf16x8 b = *(const bf16x8*)&bw;
        acc[0][nt] = __builtin_amdgcn_mfma_f32_16x16x32_bf16(a0, b, acc[0][nt], 0, 0, 0);
        acc[1][nt] = __builtin_amdgcn_mfma_f32_16x16x32_bf16(a1, b, acc[1][nt], 0, 0, 0);
      }
    }
    __syncthreads();
  }

  // epilogue: C/D layout col=lane&15, row=quad*4+reg
#pragma unroll
  for (int mt = 0; mt < 2; ++mt)
#pragma unroll
    for (int nt = 0; nt < NT; ++nt)
#pragma unroll
      for (int i = 0; i < 4; ++i) {
        int row = rbase + wrow + mt * 16 + quad * 4 + i;
        int col = nt * 16 + m16;
        if (row >= N_NODES || col >= Mstore) continue;
        float c = acc[mt][nt][i];
        if (col < M) {
          if (bias) c += bias[col];
          if (act) c = tanhf(c);
        } else {
          c = 0.f;  // zero pad for downstream K-padding
        }
        if (outfmt == 0)
          ((float*)C)[(size_t)row * ldc + col] = c;
        else
          ((unsigned short*)C)[(size_t)row * ldc + col] = f2bf(c);
      }
}

// ---------------- SPMM (bf16 in/out, fp32 accum) ---------------------------
// Hop buffers use a fixed 128-bf16 (256B) row stride so every per-edge gather
// is exactly two aligned 128B granules. Pad columns [F,128) are never read.
// cols/vals (zero-reuse streams) are loaded non-temporally and the output is
// stored non-temporally so the L2 retains only the gathered x rows (which have
// ~32x reuse, ~4x per XCD). Protecting x in L2 is the point of this version.
template <int F>
__global__ __launch_bounds__(256) void spmm_bf16_kernel(
    const int* __restrict__ rowptr, const int* __restrict__ cols,
    const float* __restrict__ vals, const unsigned short* __restrict__ xin,
    unsigned short* __restrict__ xout) {
  constexpr int FQ = F / 4;      // uint2 (4 bf16) chunks of real data per row
  constexpr int LDQ = 32;        // row stride in uint2 = 128 bf16 = 256B
  int lane = threadIdx.x & 31;
  int r = blockIdx.x * 8 + (threadIdx.x >> 5);
  if (r >= N_NODES) return;
  int e0 = rowptr[r], e1 = rowptr[r + 1];
  int myoff = (lane < FQ) ? lane : 0;
  const uint2* xin2 = (const uint2*)xin;

  float4 acc = make_float4(0.f, 0.f, 0.f, 0.f);
  int e = e0;
  while (e + 32 <= e1) {
    int   c_l = __builtin_nontemporal_load(cols + e + lane);
    float v_l = __builtin_nontemporal_load(vals + e + lane);
#pragma unroll 16
    for (int j = 0; j < 32; ++j) {
      int   c = __shfl(c_l, j, 32);
      float v = __shfl(v_l, j, 32);
      uint2 u = xin2[(size_t)c * LDQ + myoff];
      acc.x = fmaf(v, __uint_as_float(u.x << 16), acc.x);
      acc.y = fmaf(v, __uint_as_float(u.x & 0xffff0000u), acc.y);
      acc.z = fmaf(v, __uint_as_float(u.y << 16), acc.z);
      acc.w = fmaf(v, __uint_as_float(u.y & 0xffff0000u), acc.w);
    }
    e += 32;
  }
  int rem = e1 - e;
  if (rem > 0) {
    int   c_l = 0;
    float v_l = 0.f;
    if (lane < rem) {
      c_l = __builtin_nontemporal_load(cols + e + lane);
      v_l = __builtin_nontemporal_load(vals + e + lane);
    }
#pragma unroll 4
    for (int j = 0; j < rem; ++j) {
      int   c = __shfl(c_l, j, 32);
      float v = __shfl(v_l, j, 32);
      uint2 u = xin2[(size_t)c * LDQ + myoff];
      acc.x = fmaf(v, __uint_as_float(u.x << 16), acc.x);
      acc.y = fmaf(v, __uint_as_float(u.x & 0xffff0000u), acc.y);
      acc.z = fmaf(v, __uint_as_float(u.y << 16), acc.z);
      acc.w = fmaf(v, __uint_as_float(u.y & 0xffff0000u), acc.w);
    }
  }
  if (lane < FQ) {
    uint2v o;
    o.x = (unsigned)f2bf(acc.x) | ((unsigned)f2bf(acc.y) << 16);
    o.y = (unsigned)f2bf(acc.z) | ((unsigned)f2bf(acc.w) << 16);
    __builtin_nontemporal_store(o, (uint2v*)((uint2*)xout + (size_t)r * LDQ + lane));
  }
}

// -------- bias + LayerNorm + tanh (bf16 in, bf16 out, zero-padded) ---------
template <int F, int LDIN, int LDOUT>
__global__ __launch_bounds__(256) void bias_ln_tanh_kernel(
    const unsigned short* __restrict__ in, const float* __restrict__ bias,
    const float* __restrict__ g, const float* __restrict__ b,
    unsigned short* __restrict__ out) {
  int wid = threadIdx.x >> 6, lane = threadIdx.x & 63;
  int r = blockIdx.x * 4 + wid;
  if (r >= N_NODES) return;
  float x0 = 0.f, x1 = 0.f;
  if (lane < F)      x0 = bf2f(in[(size_t)r * LDIN + lane]) + bias[lane];
  if (lane + 64 < F) x1 = bf2f(in[(size_t)r * LDIN + lane + 64]) + bias[lane + 64];
  float s = x0 + x1, s2 = x0 * x0 + x1 * x1;
  for (int o = 32; o > 0; o >>= 1) {
    s  += __shfl_down(s, o, 64);
    s2 += __shfl_down(s2, o, 64);
  }
  s = __shfl(s, 0, 64); s2 = __shfl(s2, 0, 64);
  const float invF = 1.0f / (float)F;
  float mu = s * invF;
  float var = s2 * invF - mu * mu;
  float rs = rsqrtf(var + 1e-5f);
  if (lane < F)
    out[(size_t)r * LDOUT + lane] = f2bf(tanhf((x0 - mu) * rs * g[lane] + b[lane]));
  int c2 = lane + 64;
  if (c2 < F)
    out[(size_t)r * LDOUT + c2] = f2bf(tanhf((x1 - mu) * rs * g[c2] + b[c2]));
  else if (c2 < LDOUT)
    out[(size_t)r * LDOUT + c2] = 0;
}

// ---------------------------------------------------------------------------
extern "C" void kernel_launch(void* const* d_in, const int* in_sizes, int n_in,
                              void* d_out, int out_size, void* d_ws,
                              size_t ws_size, hipStream_t stream) {
  const float* x        = (const float*)d_in[0];
  const float* adj_vals = (const float*)d_in[1];
  const float* bn_g     = (const float*)d_in[2];
  const float* bn_b     = (const float*)d_in[3];
  const float* W_in     = (const float*)d_in[4];
  const float* b_in     = (const float*)d_in[5];
  const float* W1       = (const float*)d_in[6];
  const float* b1       = (const float*)d_in[7];
  const float* ln1_g    = (const float*)d_in[8];
  const float* ln1_b    = (const float*)d_in[9];
  const float* W2       = (const float*)d_in[10];
  const float* b2       = (const float*)d_in[11];
  const float* ln2_g    = (const float*)d_in[12];
  const float* ln2_b    = (const float*)d_in[13];
  const float* W_out    = (const float*)d_in[14];
  const float* b_out    = (const float*)d_in[15];
  const int*   adj_rows = (const int*)d_in[16];
  const int*   adj_cols = (const int*)d_in[17];
  float* out = (float*)d_out;

  // workspace layout (bytes)
  char* wsb = (char*)d_ws;
  size_t off = 0;
  auto alloc = [&](size_t bytes) { void* p = wsb + off; off += (bytes + 255) & ~255ull; return p; };
  float* bn_sums = (float*)alloc(512 * 4);
  float* Wf      = (float*)alloc(35840 * 4);
  float* bf      = (float*)alloc(144 * 4);
  int*   rowptr  = (int*)alloc(100016 * 4);
  uint4* Bp1 = (uint4*)alloc(8 * 10 * 64 * 16);  // K=256: 8 ktiles, NT=10
  uint4* Bp2 = (uint4*)alloc(6 * 8 * 64 * 16);   // K=192: 6 ktiles, NT=8 (real K=140)
  uint4* Bp3 = (uint4*)alloc(4 * 7 * 64 * 16);   // K=128: 4 ktiles, NT=7
  uint4* Bp4 = (uint4*)alloc(4 * 4 * 64 * 16);   // K=128: 4 ktiles, NT=4
  unsigned short* h1  = (unsigned short*)alloc((size_t)N_NODES * 192 * 2);  // [N,192]; later LN outs [N,128]
  unsigned short* zb  = (unsigned short*)alloc((size_t)N_NODES * 128 * 2);  // hop buffers, 256B-aligned rows
  unsigned short* wb  = (unsigned short*)alloc((size_t)N_NODES * 128 * 2);
  unsigned short* lnb = h1;  // reuse: h1 dead after GEMM2

  hipMemsetAsync(bn_sums, 0, 512 * sizeof(float), stream);
  hipMemsetAsync(h1, 0, (size_t)N_NODES * 192 * 2, stream);  // cols 160..191 must be 0
  bn_stats_kernel<<<1024, 256, 0, stream>>>(x, bn_sums);
  fold_bn_kernel<<<140, 256, 0, stream>>>(bn_sums, bn_g, bn_b, W_in, b_in, Wf, bf);
  build_rowptr_kernel<<<(N_NODES + 256) / 256, 256, 0, stream>>>(adj_rows, rowptr);
  // pack weights
  pack_w_kernel<<<(8 * 10 * 64 + 255) / 256, 256, 0, stream>>>(Wf,    Bp1, 256, 140, 10, 8 * 10 * 64);
  pack_w_kernel<<<(6 * 8 * 64 + 255) / 256, 256, 0, stream>>>(W1,    Bp2, 140, 120, 8,  6 * 8 * 64);
  pack_w_kernel<<<(4 * 7 * 64 + 255) / 256, 256, 0, stream>>>(W2,    Bp3, 120, 100, 7,  4 * 7 * 64);
  pack_w_kernel<<<(4 * 4 * 64 + 255) / 256, 256, 0, stream>>>(W_out, Bp4, 100, 64,  4,  4 * 4 * 64);

  const int gemm_grid = (N_NODES + 127) / 128;  // 782
  const int spmm_grid = (N_NODES + 7) / 8;      // 12500
  const int ln_grid   = (N_NODES + 3) / 4;      // 25000

  // h1 = tanh(bn(x) @ Wf + bf)  [N,192] bf16; cols 140..159 zeroed here, 160..191 by memset
  mfma_gemm_kernel<256, 10, float><<<gemm_grid, 256, 0, stream>>>(
      x, Bp1, bf, h1, 140, 160, 192, 1, 1);
  // zb = h1 @ W1 (bias deferred)  [N,128] bf16, cols 120..127 zeroed (KPAD=192)
  mfma_gemm_kernel<192, 8, unsigned short><<<gemm_grid, 256, 0, stream>>>(
      h1, Bp2, nullptr, zb, 120, 128, 128, 0, 1);
  // 4 hops at F=120 (256B-aligned rows)
  spmm_bf16_kernel<120><<<spmm_grid, 256, 0, stream>>>(rowptr, adj_cols, adj_vals, zb, wb);
  spmm_bf16_kernel<120><<<spmm_grid, 256, 0, stream>>>(rowptr, adj_cols, adj_vals, wb, zb);
  spmm_bf16_kernel<120><<<spmm_grid, 256, 0, stream>>>(rowptr, adj_cols, adj_vals, zb, wb);
  spmm_bf16_kernel<120><<<spmm_grid, 256, 0, stream>>>(rowptr, adj_cols, adj_vals, wb, zb);
  // lnb = tanh(LN(zb + b1))  [N,128] bf16, cols 120..127 = 0
  bias_ln_tanh_kernel<120, 128, 128><<<ln_grid, 256, 0, stream>>>(zb, b1, ln1_g, ln1_b, lnb);
  // zb = lnb @ W2 (bias deferred)  [N,128-stride] bf16; cols 100..111 zeroed, 112..127 never read
  mfma_gemm_kernel<128, 7, unsigned short><<<gemm_grid, 256, 0, stream>>>(
      lnb, Bp3, nullptr, zb, 100, 112, 128, 0, 1);
  // 4 hops at F=100 (256B-aligned rows)
  spmm_bf16_kernel<100><<<spmm_grid, 256, 0, stream>>>(rowptr, adj_cols, adj_vals, zb, wb);
  spmm_bf16_kernel<100><<<spmm_grid, 256, 0, stream>>>(rowptr, adj_cols, adj_vals, wb, zb);
  spmm_bf16_kernel<100><<<spmm_grid, 256, 0, stream>>>(rowptr, adj_cols, adj_vals, zb, wb);
  spmm_bf16_kernel<100><<<spmm_grid, 256, 0, stream>>>(rowptr, adj_cols, adj_vals, wb, zb);
  // lnb = tanh(LN(zb + b2))  [N,128] bf16, cols 100..127 = 0
  bias_ln_tanh_kernel<100, 128, 128><<<ln_grid, 256, 0, stream>>>(zb, b2, ln2_g, ln2_b, lnb);
  // out = lnb @ W_out + b_out  [N,64] fp32
  mfma_gemm_kernel<128, 4, unsigned short><<<gemm_grid, 256, 0, stream>>>(
      lnb, Bp4, b_out, out, 64, 64, 64, 0, 0);
}

// Round 6
// 1481.316 us; speedup vs baseline: 1.2152x; 1.2152x over previous
//
#include <hip/hip_runtime.h>
#include <hip/hip_bf16.h>
#include <math.h>

#define N_NODES 100000
#define E_EDGES 3200000
#define IN_DIM  256

typedef __attribute__((ext_vector_type(8))) short bf16x8;
typedef __attribute__((ext_vector_type(4))) float f32x4;

// ---- bf16 helpers ---------------------------------------------------------
__device__ __forceinline__ unsigned short f2bf(float f) {
  unsigned u = __float_as_uint(f);
  u += 0x7fffu + ((u >> 16) & 1u);   // RTNE
  return (unsigned short)(u >> 16);
}
__device__ __forceinline__ float bf2f(unsigned short h) {
  return __uint_as_float(((unsigned)h) << 16);
}

// ---------------- BN column stats (sum, sumsq per feature) ----------------
__global__ __launch_bounds__(256) void bn_stats_kernel(
    const float* __restrict__ x, float* __restrict__ sums /*512 floats*/) {
  int c = threadIdx.x;
  float s = 0.f, s2 = 0.f;
  for (int r = blockIdx.x; r < N_NODES; r += gridDim.x) {
    float v = x[(size_t)r * IN_DIM + c];
    s += v; s2 += v * v;
  }
  atomicAdd(&sums[c], s);
  atomicAdd(&sums[256 + c], s2);
}

// ------------- fold BN affine into W_in / b_in ----------------------------
__global__ __launch_bounds__(256) void fold_bn_kernel(
    const float* __restrict__ sums, const float* __restrict__ bn_g,
    const float* __restrict__ bn_b, const float* __restrict__ W_in,
    const float* __restrict__ b_in, float* __restrict__ Wf,
    float* __restrict__ bf) {
  int j = blockIdx.x;   // out col 0..139
  int c = threadIdx.x;  // in col 0..255
  const float invN = 1.0f / (float)N_NODES;
  float mu  = sums[c] * invN;
  float var = sums[256 + c] * invN - mu * mu;
  float s   = bn_g[c] * rsqrtf(var + 1e-5f);
  float t   = bn_b[c] - mu * s;
  float w   = W_in[(size_t)c * 140 + j];
  Wf[(size_t)c * 140 + j] = s * w;
  float v = t * w;
  for (int o = 32; o > 0; o >>= 1) v += __shfl_down(v, o, 64);
  __shared__ float red[4];
  int wid = threadIdx.x >> 6, lane = threadIdx.x & 63;
  if (lane == 0) red[wid] = v;
  __syncthreads();
  if (threadIdx.x == 0)
    bf[j] = b_in[j] + red[0] + red[1] + red[2] + red[3];
}

// ---------------- CSR row_ptr from sorted rows (binary search) -------------
__global__ __launch_bounds__(256) void build_rowptr_kernel(
    const int* __restrict__ rows, int* __restrict__ rowptr) {
  int r = blockIdx.x * 256 + threadIdx.x;
  if (r > N_NODES) return;
  int lo = 0, hi = E_EDGES;
  while (lo < hi) {
    int mid = (lo + hi) >> 1;
    if (rows[mid] < r) lo = mid + 1; else hi = mid;
  }
  rowptr[r] = lo;
}

// ------- pack fp32 W[K,M] into MFMA B-fragment order, bf16, zero-padded ----
// Bp[(kt*NT + nt)*64 + lane] = uint4 of 8 bf16: B[kt*32+(lane>>4)*8+j][nt*16+(lane&15)]
__global__ __launch_bounds__(256) void pack_w_kernel(
    const float* __restrict__ W, uint4* __restrict__ Bp, int K, int M, int NT,
    int total) {
  int id = blockIdx.x * 256 + threadIdx.x;
  if (id >= total) return;
  int lane = id & 63;
  int nt = (id >> 6) % NT;
  int kt = id / (64 * NT);
  int n = nt * 16 + (lane & 15);
  int kbase = kt * 32 + (lane >> 4) * 8;
  unsigned short v[8];
#pragma unroll
  for (int j = 0; j < 8; ++j) {
    int k = kbase + j;
    v[j] = (k < K && n < M) ? f2bf(W[(size_t)k * M + n]) : (unsigned short)0;
  }
  Bp[id] = *(uint4*)v;
}

// ---------------- MFMA bf16 GEMM -------------------------------------------
// C[N, ldc] = act(A[N, KPAD] @ B[KPAD, NT*16] + bias); A fp32 or bf16.
// KPAD must be a multiple of 64. 256 thr = 4 waves; block tile 128 rows.
template <int KPAD, int NT, typename AT>
__global__ __launch_bounds__(256) void mfma_gemm_kernel(
    const AT* __restrict__ A, const uint4* __restrict__ Bp,
    const float* __restrict__ bias, void* __restrict__ C,
    int M, int Mstore, int ldc, int act, int outfmt) {
  static_assert(KPAD % 64 == 0, "KPAD must be a multiple of 64");
  __shared__ unsigned short As[128 * 72];  // 64-k chunk, stride 72 (2-way only)
  int tid = threadIdx.x;
  int lane = tid & 63;
  int wave = tid >> 6;
  int quad = lane >> 4, m16 = lane & 15;
  int rbase = blockIdx.x * 128;
  int wrow = wave * 32;

  f32x4 acc[2][NT];
#pragma unroll
  for (int mt = 0; mt < 2; ++mt)
#pragma unroll
    for (int nt = 0; nt < NT; ++nt)
      acc[mt][nt] = (f32x4){0.f, 0.f, 0.f, 0.f};

  for (int k0 = 0; k0 < KPAD; k0 += 64) {
    if constexpr (sizeof(AT) == 2) {
      int r0 = tid >> 3, q = tid & 7;
#pragma unroll
      for (int it = 0; it < 4; ++it) {
        int r = r0 + it * 32;
        int row = rbase + r;
        uint4 v = make_uint4(0u, 0u, 0u, 0u);
        if (row < N_NODES)
          v = *(const uint4*)((const unsigned short*)A + (size_t)row * KPAD + k0 + q * 8);
        *(uint4*)&As[r * 72 + q * 8] = v;
      }
    } else {
      int r0 = tid >> 4, fq = tid & 15;
#pragma unroll
      for (int it = 0; it < 8; ++it) {
        int r = r0 + it * 16;
        int row = rbase + r;
        float4 v = make_float4(0.f, 0.f, 0.f, 0.f);
        if (row < N_NODES)
          v = *(const float4*)((const float*)A + (size_t)row * KPAD + k0 + fq * 4);
        unsigned short p[4] = {f2bf(v.x), f2bf(v.y), f2bf(v.z), f2bf(v.w)};
        *(uint2*)&As[r * 72 + fq * 4] = *(uint2*)p;
      }
    }
    __syncthreads();
#pragma unroll
    for (int s = 0; s < 2; ++s) {
      int kt = (k0 >> 5) + s;
      bf16x8 a0 = *(const bf16x8*)&As[(wrow + m16) * 72 + s * 32 + quad * 8];
      bf16x8 a1 = *(const bf16x8*)&As[(wrow + 16 + m16) * 72 + s * 32 + quad * 8];
#pragma unroll
      for (int nt = 0; nt < NT; ++nt) {
        uint4 bw = Bp[(size_t)(kt * NT + nt) * 64 + lane];
        bf16x8 b = *(const bf16x8*)&bw;
        acc[0][nt] = __builtin_amdgcn_mfma_f32_16x16x32_bf16(a0, b, acc[0][nt], 0, 0, 0);
        acc[1][nt] = __builtin_amdgcn_mfma_f32_16x16x32_bf16(a1, b, acc[1][nt], 0, 0, 0);
      }
    }
    __syncthreads();
  }

  // epilogue: C/D layout col=lane&15, row=quad*4+reg
#pragma unroll
  for (int mt = 0; mt < 2; ++mt)
#pragma unroll
    for (int nt = 0; nt < NT; ++nt)
#pragma unroll
      for (int i = 0; i < 4; ++i) {
        int row = rbase + wrow + mt * 16 + quad * 4 + i;
        int col = nt * 16 + m16;
        if (row >= N_NODES || col >= Mstore) continue;
        float c = acc[mt][nt][i];
        if (col < M) {
          if (bias) c += bias[col];
          if (act) c = tanhf(c);
        } else {
          c = 0.f;  // zero pad for downstream K-padding
        }
        if (outfmt == 0)
          ((float*)C)[(size_t)row * ldc + col] = c;
        else
          ((unsigned short*)C)[(size_t)row * ldc + col] = f2bf(c);
      }
}

// ---------------- SPMM (bf16 in/out, fp32 accum) ---------------------------
// 256B-aligned rows (two 128B granules per gather). Round-2 change, still
// unmeasured (resubmitted unchanged; infra failures rounds 3-5): explicit
// 8-deep MLP — all 8 gather loads of a group are issued into named registers
// before any FMA consumes them. Previous measured version compiled to 16
// VGPRs = ~1 outstanding gather/wave = latency-serialized (170us/hop,
// VALUBusy 26%, nothing saturated). cols/vals stay nontemporal (zero reuse);
// output store is a NORMAL store (it is the next hop's gather input).
template <int F>
__global__ __launch_bounds__(256) void spmm_bf16_kernel(
    const int* __restrict__ rowptr, const int* __restrict__ cols,
    const float* __restrict__ vals, const unsigned short* __restrict__ xin,
    unsigned short* __restrict__ xout) {
  constexpr int FQ = F / 4;      // uint2 (4 bf16) chunks of real data per row
  constexpr int LDQ = 32;        // row stride in uint2 = 128 bf16 = 256B
  int lane = threadIdx.x & 31;
  int r = blockIdx.x * 8 + (threadIdx.x >> 5);
  if (r >= N_NODES) return;
  int e0 = rowptr[r], e1 = rowptr[r + 1];
  int myoff = (lane < FQ) ? lane : 0;
  const uint2* xin2 = (const uint2*)xin;

  float4 acc = make_float4(0.f, 0.f, 0.f, 0.f);

  for (int eb = e0; eb < e1; eb += 32) {
    int n = e1 - eb; if (n > 32) n = 32;
    int   c_l = 0;
    float v_l = 0.f;
    if (lane < n) {
      c_l = __builtin_nontemporal_load(cols + eb + lane);
      v_l = __builtin_nontemporal_load(vals + eb + lane);
    }
#pragma unroll
    for (int g = 0; g < 4; ++g) {
      if (g * 8 < n) {  // per-group guard; inactive tail lanes have v=0,c=0
        uint2 u[8];
        float vv[8];
#pragma unroll
        for (int jj = 0; jj < 8; ++jj) {
          int c  = __shfl(c_l, g * 8 + jj, 32);
          vv[jj] = __shfl(v_l, g * 8 + jj, 32);
          u[jj]  = xin2[(size_t)c * LDQ + myoff];
        }
#pragma unroll
        for (int jj = 0; jj < 8; ++jj) {
          acc.x = fmaf(vv[jj], __uint_as_float(u[jj].x << 16), acc.x);
          acc.y = fmaf(vv[jj], __uint_as_float(u[jj].x & 0xffff0000u), acc.y);
          acc.z = fmaf(vv[jj], __uint_as_float(u[jj].y << 16), acc.z);
          acc.w = fmaf(vv[jj], __uint_as_float(u[jj].y & 0xffff0000u), acc.w);
        }
      }
    }
  }

  if (lane < FQ) {
    uint2 o;
    o.x = (unsigned)f2bf(acc.x) | ((unsigned)f2bf(acc.y) << 16);
    o.y = (unsigned)f2bf(acc.z) | ((unsigned)f2bf(acc.w) << 16);
    ((uint2*)xout)[(size_t)r * LDQ + lane] = o;
  }
}

// -------- bias + LayerNorm + tanh (bf16 in, bf16 out, zero-padded) ---------
template <int F, int LDIN, int LDOUT>
__global__ __launch_bounds__(256) void bias_ln_tanh_kernel(
    const unsigned short* __restrict__ in, const float* __restrict__ bias,
    const float* __restrict__ g, const float* __restrict__ b,
    unsigned short* __restrict__ out) {
  int wid = threadIdx.x >> 6, lane = threadIdx.x & 63;
  int r = blockIdx.x * 4 + wid;
  if (r >= N_NODES) return;
  float x0 = 0.f, x1 = 0.f;
  if (lane < F)      x0 = bf2f(in[(size_t)r * LDIN + lane]) + bias[lane];
  if (lane + 64 < F) x1 = bf2f(in[(size_t)r * LDIN + lane + 64]) + bias[lane + 64];
  float s = x0 + x1, s2 = x0 * x0 + x1 * x1;
  for (int o = 32; o > 0; o >>= 1) {
    s  += __shfl_down(s, o, 64);
    s2 += __shfl_down(s2, o, 64);
  }
  s = __shfl(s, 0, 64); s2 = __shfl(s2, 0, 64);
  const float invF = 1.0f / (float)F;
  float mu = s * invF;
  float var = s2 * invF - mu * mu;
  float rs = rsqrtf(var + 1e-5f);
  if (lane < F)
    out[(size_t)r * LDOUT + lane] = f2bf(tanhf((x0 - mu) * rs * g[lane] + b[lane]));
  int c2 = lane + 64;
  if (c2 < F)
    out[(size_t)r * LDOUT + c2] = f2bf(tanhf((x1 - mu) * rs * g[c2] + b[c2]));
  else if (c2 < LDOUT)
    out[(size_t)r * LDOUT + c2] = 0;
}

// ---------------------------------------------------------------------------
extern "C" void kernel_launch(void* const* d_in, const int* in_sizes, int n_in,
                              void* d_out, int out_size, void* d_ws,
                              size_t ws_size, hipStream_t stream) {
  const float* x        = (const float*)d_in[0];
  const float* adj_vals = (const float*)d_in[1];
  const float* bn_g     = (const float*)d_in[2];
  const float* bn_b     = (const float*)d_in[3];
  const float* W_in     = (const float*)d_in[4];
  const float* b_in     = (const float*)d_in[5];
  const float* W1       = (const float*)d_in[6];
  const float* b1       = (const float*)d_in[7];
  const float* ln1_g    = (const float*)d_in[8];
  const float* ln1_b    = (const float*)d_in[9];
  const float* W2       = (const float*)d_in[10];
  const float* b2       = (const float*)d_in[11];
  const float* ln2_g    = (const float*)d_in[12];
  const float* ln2_b    = (const float*)d_in[13];
  const float* W_out    = (const float*)d_in[14];
  const float* b_out    = (const float*)d_in[15];
  const int*   adj_rows = (const int*)d_in[16];
  const int*   adj_cols = (const int*)d_in[17];
  float* out = (float*)d_out;

  // workspace layout (bytes)
  char* wsb = (char*)d_ws;
  size_t off = 0;
  auto alloc = [&](size_t bytes) { void* p = wsb + off; off += (bytes + 255) & ~255ull; return p; };
  float* bn_sums = (float*)alloc(512 * 4);
  float* Wf      = (float*)alloc(35840 * 4);
  float* bf      = (float*)alloc(144 * 4);
  int*   rowptr  = (int*)alloc(100016 * 4);
  uint4* Bp1 = (uint4*)alloc(8 * 10 * 64 * 16);  // K=256: 8 ktiles, NT=10
  uint4* Bp2 = (uint4*)alloc(6 * 8 * 64 * 16);   // K=192: 6 ktiles, NT=8 (real K=140)
  uint4* Bp3 = (uint4*)alloc(4 * 7 * 64 * 16);   // K=128: 4 ktiles, NT=7
  uint4* Bp4 = (uint4*)alloc(4 * 4 * 64 * 16);   // K=128: 4 ktiles, NT=4
  unsigned short* h1  = (unsigned short*)alloc((size_t)N_NODES * 192 * 2);  // [N,192]; later LN outs [N,128]
  unsigned short* zb  = (unsigned short*)alloc((size_t)N_NODES * 128 * 2);  // hop buffers, 256B-aligned rows
  unsigned short* wb  = (unsigned short*)alloc((size_t)N_NODES * 128 * 2);
  unsigned short* lnb = h1;  // reuse: h1 dead after GEMM2

  hipMemsetAsync(bn_sums, 0, 512 * sizeof(float), stream);
  hipMemsetAsync(h1, 0, (size_t)N_NODES * 192 * 2, stream);  // cols 160..191 must be 0
  bn_stats_kernel<<<1024, 256, 0, stream>>>(x, bn_sums);
  fold_bn_kernel<<<140, 256, 0, stream>>>(bn_sums, bn_g, bn_b, W_in, b_in, Wf, bf);
  build_rowptr_kernel<<<(N_NODES + 256) / 256, 256, 0, stream>>>(adj_rows, rowptr);
  // pack weights
  pack_w_kernel<<<(8 * 10 * 64 + 255) / 256, 256, 0, stream>>>(Wf,    Bp1, 256, 140, 10, 8 * 10 * 64);
  pack_w_kernel<<<(6 * 8 * 64 + 255) / 256, 256, 0, stream>>>(W1,    Bp2, 140, 120, 8,  6 * 8 * 64);
  pack_w_kernel<<<(4 * 7 * 64 + 255) / 256, 256, 0, stream>>>(W2,    Bp3, 120, 100, 7,  4 * 7 * 64);
  pack_w_kernel<<<(4 * 4 * 64 + 255) / 256, 256, 0, stream>>>(W_out, Bp4, 100, 64,  4,  4 * 4 * 64);

  const int gemm_grid = (N_NODES + 127) / 128;  // 782
  const int spmm_grid = (N_NODES + 7) / 8;      // 12500
  const int ln_grid   = (N_NODES + 3) / 4;      // 25000

  // h1 = tanh(bn(x) @ Wf + bf)  [N,192] bf16; cols 140..159 zeroed here, 160..191 by memset
  mfma_gemm_kernel<256, 10, float><<<gemm_grid, 256, 0, stream>>>(
      x, Bp1, bf, h1, 140, 160, 192, 1, 1);
  // zb = h1 @ W1 (bias deferred)  [N,128] bf16, cols 120..127 zeroed (KPAD=192)
  mfma_gemm_kernel<192, 8, unsigned short><<<gemm_grid, 256, 0, stream>>>(
      h1, Bp2, nullptr, zb, 120, 128, 128, 0, 1);
  // 4 hops at F=120 (256B-aligned rows)
  spmm_bf16_kernel<120><<<spmm_grid, 256, 0, stream>>>(rowptr, adj_cols, adj_vals, zb, wb);
  spmm_bf16_kernel<120><<<spmm_grid, 256, 0, stream>>>(rowptr, adj_cols, adj_vals, wb, zb);
  spmm_bf16_kernel<120><<<spmm_grid, 256, 0, stream>>>(rowptr, adj_cols, adj_vals, zb, wb);
  spmm_bf16_kernel<120><<<spmm_grid, 256, 0, stream>>>(rowptr, adj_cols, adj_vals, wb, zb);
  // lnb = tanh(LN(zb + b1))  [N,128] bf16, cols 120..127 = 0
  bias_ln_tanh_kernel<120, 128, 128><<<ln_grid, 256, 0, stream>>>(zb, b1, ln1_g, ln1_b, lnb);
  // zb = lnb @ W2 (bias deferred)  [N,128-stride] bf16; cols 100..111 zeroed, 112..127 never read
  mfma_gemm_kernel<128, 7, unsigned short><<<gemm_grid, 256, 0, stream>>>(
      lnb, Bp3, nullptr, zb, 100, 112, 128, 0, 1);
  // 4 hops at F=100 (256B-aligned rows)
  spmm_bf16_kernel<100><<<spmm_grid, 256, 0, stream>>>(rowptr, adj_cols, adj_vals, zb, wb);
  spmm_bf16_kernel<100><<<spmm_grid, 256, 0, stream>>>(rowptr, adj_cols, adj_vals, wb, zb);
  spmm_bf16_kernel<100><<<spmm_grid, 256, 0, stream>>>(rowptr, adj_cols, adj_vals, zb, wb);
  spmm_bf16_kernel<100><<<spmm_grid, 256, 0, stream>>>(rowptr, adj_cols, adj_vals, wb, zb);
  // lnb = tanh(LN(zb + b2))  [N,128] bf16, cols 100..127 = 0
  bias_ln_tanh_kernel<100, 128, 128><<<ln_grid, 256, 0, stream>>>(zb, b2, ln2_g, ln2_b, lnb);
  // out = lnb @ W_out + b_out  [N,64] fp32
  mfma_gemm_kernel<128, 4, unsigned short><<<gemm_grid, 256, 0, stream>>>(
      lnb, Bp4, b_out, out, 64, 64, 64, 0, 0);
}

// Round 10
// 1344.220 us; speedup vs baseline: 1.3391x; 1.1020x over previous
//
#include <hip/hip_runtime.h>
#include <hip/hip_bf16.h>
#include <math.h>

#define N_NODES 100000
#define E_EDGES 3200000
#define IN_DIM  256

typedef __attribute__((ext_vector_type(8))) short bf16x8;
typedef __attribute__((ext_vector_type(4))) float f32x4;

// ---- bf16 helpers ---------------------------------------------------------
__device__ __forceinline__ unsigned short f2bf(float f) {
  unsigned u = __float_as_uint(f);
  u += 0x7fffu + ((u >> 16) & 1u);   // RTNE
  return (unsigned short)(u >> 16);
}
__device__ __forceinline__ float bf2f(unsigned short h) {
  return __uint_as_float(((unsigned)h) << 16);
}

// ---------------- BN column stats (sum, sumsq per feature) ----------------
__global__ __launch_bounds__(256) void bn_stats_kernel(
    const float* __restrict__ x, float* __restrict__ sums /*512 floats*/) {
  int c = threadIdx.x;
  float s = 0.f, s2 = 0.f;
  for (int r = blockIdx.x; r < N_NODES; r += gridDim.x) {
    float v = x[(size_t)r * IN_DIM + c];
    s += v; s2 += v * v;
  }
  atomicAdd(&sums[c], s);
  atomicAdd(&sums[256 + c], s2);
}

// ------------- fold BN affine into W_in / b_in ----------------------------
__global__ __launch_bounds__(256) void fold_bn_kernel(
    const float* __restrict__ sums, const float* __restrict__ bn_g,
    const float* __restrict__ bn_b, const float* __restrict__ W_in,
    const float* __restrict__ b_in, float* __restrict__ Wf,
    float* __restrict__ bf) {
  int j = blockIdx.x;   // out col 0..139
  int c = threadIdx.x;  // in col 0..255
  const float invN = 1.0f / (float)N_NODES;
  float mu  = sums[c] * invN;
  float var = sums[256 + c] * invN - mu * mu;
  float s   = bn_g[c] * rsqrtf(var + 1e-5f);
  float t   = bn_b[c] - mu * s;
  float w   = W_in[(size_t)c * 140 + j];
  Wf[(size_t)c * 140 + j] = s * w;
  float v = t * w;
  for (int o = 32; o > 0; o >>= 1) v += __shfl_down(v, o, 64);
  __shared__ float red[4];
  int wid = threadIdx.x >> 6, lane = threadIdx.x & 63;
  if (lane == 0) red[wid] = v;
  __syncthreads();
  if (threadIdx.x == 0)
    bf[j] = b_in[j] + red[0] + red[1] + red[2] + red[3];
}

// ---------------- CSR row_ptr from sorted rows (binary search) -------------
__global__ __launch_bounds__(256) void build_rowptr_kernel(
    const int* __restrict__ rows, int* __restrict__ rowptr) {
  int r = blockIdx.x * 256 + threadIdx.x;
  if (r > N_NODES) return;
  int lo = 0, hi = E_EDGES;
  while (lo < hi) {
    int mid = (lo + hi) >> 1;
    if (rows[mid] < r) lo = mid + 1; else hi = mid;
  }
  rowptr[r] = lo;
}

// ------- pack fp32 W[K,M] into MFMA B-fragment order, bf16, zero-padded ----
// Bp[(kt*NT + nt)*64 + lane] = uint4 of 8 bf16: B[kt*32+(lane>>4)*8+j][nt*16+(lane&15)]
__global__ __launch_bounds__(256) void pack_w_kernel(
    const float* __restrict__ W, uint4* __restrict__ Bp, int K, int M, int NT,
    int total) {
  int id = blockIdx.x * 256 + threadIdx.x;
  if (id >= total) return;
  int lane = id & 63;
  int nt = (id >> 6) % NT;
  int kt = id / (64 * NT);
  int n = nt * 16 + (lane & 15);
  int kbase = kt * 32 + (lane >> 4) * 8;
  unsigned short v[8];
#pragma unroll
  for (int j = 0; j < 8; ++j) {
    int k = kbase + j;
    v[j] = (k < K && n < M) ? f2bf(W[(size_t)k * M + n]) : (unsigned short)0;
  }
  Bp[id] = *(uint4*)v;
}

// ---------------- MFMA bf16 GEMM (barrier-free, no LDS) --------------------
// r6-measured staged version: 147us GEMM1, MfmaUtil 2.1%, VALUBusy 13%,
// Occupancy 20% -> latency-bound on the per-K-step global->LDS ->
// syncthreads(vmcnt0 drain) -> MFMA -> syncthreads cycle at ~3 waves/SIMD.
// Fix (unmeasured, resubmitted): each lane's A-fragment is a contiguous
// 16B span of its row (A[row][k0+quad*8..+8]) -> read DIRECTLY from global;
// B fragments from global (L2-resident packed Bp). No LDS, no barriers;
// waves independent; unroll-2 K-loop pipelines next-iter loads under MFMAs.
template <int KT, int NT, typename AT>
__global__ __launch_bounds__(256) void mfma_gemm_kernel(
    const AT* __restrict__ A, const uint4* __restrict__ Bp,
    const float* __restrict__ bias, void* __restrict__ C,
    int M, int Mstore, int ldc, int act, int outfmt) {
  constexpr int KPAD = KT * 32;
  int tid = threadIdx.x;
  int lane = tid & 63;
  int wave = tid >> 6;
  int quad = lane >> 4, m16 = lane & 15;
  int rbase = blockIdx.x * 128 + wave * 32;  // this wave's 32 output rows
  int row0 = rbase + m16;
  int row1 = rbase + 16 + m16;
  bool ok0 = row0 < N_NODES, ok1 = row1 < N_NODES;

  f32x4 acc[2][NT];
#pragma unroll
  for (int mt = 0; mt < 2; ++mt)
#pragma unroll
    for (int nt = 0; nt < NT; ++nt)
      acc[mt][nt] = (f32x4){0.f, 0.f, 0.f, 0.f};

#pragma unroll 2
  for (int kt = 0; kt < KT; ++kt) {
    int k0 = kt * 32;
    bf16x8 a0, a1;
    if constexpr (sizeof(AT) == 2) {
      uint4 v0 = make_uint4(0u, 0u, 0u, 0u), v1 = v0;
      if (ok0) v0 = *(const uint4*)((const unsigned short*)A + (size_t)row0 * KPAD + k0 + quad * 8);
      if (ok1) v1 = *(const uint4*)((const unsigned short*)A + (size_t)row1 * KPAD + k0 + quad * 8);
      a0 = *(const bf16x8*)&v0;
      a1 = *(const bf16x8*)&v1;
    } else {
      float4 p0 = make_float4(0.f, 0.f, 0.f, 0.f), p1 = p0, q0 = p0, q1 = p0;
      if (ok0) {
        p0 = *(const float4*)((const float*)A + (size_t)row0 * KPAD + k0 + quad * 8);
        q0 = *(const float4*)((const float*)A + (size_t)row0 * KPAD + k0 + quad * 8 + 4);
      }
      if (ok1) {
        p1 = *(const float4*)((const float*)A + (size_t)row1 * KPAD + k0 + quad * 8);
        q1 = *(const float4*)((const float*)A + (size_t)row1 * KPAD + k0 + quad * 8 + 4);
      }
      unsigned short w0[8] = {f2bf(p0.x), f2bf(p0.y), f2bf(p0.z), f2bf(p0.w),
                              f2bf(q0.x), f2bf(q0.y), f2bf(q0.z), f2bf(q0.w)};
      unsigned short w1[8] = {f2bf(p1.x), f2bf(p1.y), f2bf(p1.z), f2bf(p1.w),
                              f2bf(q1.x), f2bf(q1.y), f2bf(q1.z), f2bf(q1.w)};
      a0 = *(const bf16x8*)w0;
      a1 = *(const bf16x8*)w1;
    }
    const uint4* bp = Bp + (size_t)(kt * NT) * 64 + lane;
#pragma unroll
    for (int nt = 0; nt < NT; ++nt) {
      uint4 bw = bp[(size_t)nt * 64];
      bf16x8 b = *(const bf16x8*)&bw;
      acc[0][nt] = __builtin_amdgcn_mfma_f32_16x16x32_bf16(a0, b, acc[0][nt], 0, 0, 0);
      acc[1][nt] = __builtin_amdgcn_mfma_f32_16x16x32_bf16(a1, b, acc[1][nt], 0, 0, 0);
    }
  }

  // epilogue: C/D layout col=lane&15, row=quad*4+reg
#pragma unroll
  for (int mt = 0; mt < 2; ++mt)
#pragma unroll
    for (int nt = 0; nt < NT; ++nt)
#pragma unroll
      for (int i = 0; i < 4; ++i) {
        int row = rbase + mt * 16 + quad * 4 + i;
        int col = nt * 16 + m16;
        if (row >= N_NODES || col >= Mstore) continue;
        float c = acc[mt][nt][i];
        if (col < M) {
          if (bias) c += bias[col];
          if (act) c = tanhf(c);
        } else {
          c = 0.f;  // zero pad for downstream K-padding
        }
        if (outfmt == 0)
          ((float*)C)[(size_t)row * ldc + col] = c;
        else
          ((unsigned short*)C)[(size_t)row * ldc + col] = f2bf(c);
      }
}

// ---------------- SPMM (bf16 in/out, fp32 accum) ---------------------------
// 256B-aligned rows (two 128B granules per gather). MEASURED GOOD (r6):
// 8-deep explicit gather MLP took hops from 170us (16 VGPR, 1 outstanding
// load) out of the top-5 entirely (<=147us; est ~135us from r6 budget).
// FROZEN this round so the next successful bench reveals its true per-hop
// time before any further SPMM restructure.
template <int F>
__global__ __launch_bounds__(256) void spmm_bf16_kernel(
    const int* __restrict__ rowptr, const int* __restrict__ cols,
    const float* __restrict__ vals, const unsigned short* __restrict__ xin,
    unsigned short* __restrict__ xout) {
  constexpr int FQ = F / 4;      // uint2 (4 bf16) chunks of real data per row
  constexpr int LDQ = 32;        // row stride in uint2 = 128 bf16 = 256B
  int lane = threadIdx.x & 31;
  int r = blockIdx.x * 8 + (threadIdx.x >> 5);
  if (r >= N_NODES) return;
  int e0 = rowptr[r], e1 = rowptr[r + 1];
  int myoff = (lane < FQ) ? lane : 0;
  const uint2* xin2 = (const uint2*)xin;

  float4 acc = make_float4(0.f, 0.f, 0.f, 0.f);

  for (int eb = e0; eb < e1; eb += 32) {
    int n = e1 - eb; if (n > 32) n = 32;
    int   c_l = 0;
    float v_l = 0.f;
    if (lane < n) {
      c_l = __builtin_nontemporal_load(cols + eb + lane);
      v_l = __builtin_nontemporal_load(vals + eb + lane);
    }
#pragma unroll
    for (int g = 0; g < 4; ++g) {
      if (g * 8 < n) {  // per-group guard; inactive tail lanes have v=0,c=0
        uint2 u[8];
        float vv[8];
#pragma unroll
        for (int jj = 0; jj < 8; ++jj) {
          int c  = __shfl(c_l, g * 8 + jj, 32);
          vv[jj] = __shfl(v_l, g * 8 + jj, 32);
          u[jj]  = xin2[(size_t)c * LDQ + myoff];
        }
#pragma unroll
        for (int jj = 0; jj < 8; ++jj) {
          acc.x = fmaf(vv[jj], __uint_as_float(u[jj].x << 16), acc.x);
          acc.y = fmaf(vv[jj], __uint_as_float(u[jj].x & 0xffff0000u), acc.y);
          acc.z = fmaf(vv[jj], __uint_as_float(u[jj].y << 16), acc.z);
          acc.w = fmaf(vv[jj], __uint_as_float(u[jj].y & 0xffff0000u), acc.w);
        }
      }
    }
  }

  if (lane < FQ) {
    uint2 o;
    o.x = (unsigned)f2bf(acc.x) | ((unsigned)f2bf(acc.y) << 16);
    o.y = (unsigned)f2bf(acc.z) | ((unsigned)f2bf(acc.w) << 16);
    ((uint2*)xout)[(size_t)r * LDQ + lane] = o;
  }
}

// -------- bias + LayerNorm + tanh (bf16 in, bf16 out, zero-padded) ---------
template <int F, int LDIN, int LDOUT>
__global__ __launch_bounds__(256) void bias_ln_tanh_kernel(
    const unsigned short* __restrict__ in, const float* __restrict__ bias,
    const float* __restrict__ g, const float* __restrict__ b,
    unsigned short* __restrict__ out) {
  int wid = threadIdx.x >> 6, lane = threadIdx.x & 63;
  int r = blockIdx.x * 4 + wid;
  if (r >= N_NODES) return;
  float x0 = 0.f, x1 = 0.f;
  if (lane < F)      x0 = bf2f(in[(size_t)r * LDIN + lane]) + bias[lane];
  if (lane + 64 < F) x1 = bf2f(in[(size_t)r * LDIN + lane + 64]) + bias[lane + 64];
  float s = x0 + x1, s2 = x0 * x0 + x1 * x1;
  for (int o = 32; o > 0; o >>= 1) {
    s  += __shfl_down(s, o, 64);
    s2 += __shfl_down(s2, o, 64);
  }
  s = __shfl(s, 0, 64); s2 = __shfl(s2, 0, 64);
  const float invF = 1.0f / (float)F;
  float mu = s * invF;
  float var = s2 * invF - mu * mu;
  float rs = rsqrtf(var + 1e-5f);
  if (lane < F)
    out[(size_t)r * LDOUT + lane] = f2bf(tanhf((x0 - mu) * rs * g[lane] + b[lane]));
  int c2 = lane + 64;
  if (c2 < F)
    out[(size_t)r * LDOUT + c2] = f2bf(tanhf((x1 - mu) * rs * g[c2] + b[c2]));
  else if (c2 < LDOUT)
    out[(size_t)r * LDOUT + c2] = 0;
}

// ---------------------------------------------------------------------------
extern "C" void kernel_launch(void* const* d_in, const int* in_sizes, int n_in,
                              void* d_out, int out_size, void* d_ws,
                              size_t ws_size, hipStream_t stream) {
  const float* x        = (const float*)d_in[0];
  const float* adj_vals = (const float*)d_in[1];
  const float* bn_g     = (const float*)d_in[2];
  const float* bn_b     = (const float*)d_in[3];
  const float* W_in     = (const float*)d_in[4];
  const float* b_in     = (const float*)d_in[5];
  const float* W1       = (const float*)d_in[6];
  const float* b1       = (const float*)d_in[7];
  const float* ln1_g    = (const float*)d_in[8];
  const float* ln1_b    = (const float*)d_in[9];
  const float* W2       = (const float*)d_in[10];
  const float* b2       = (const float*)d_in[11];
  const float* ln2_g    = (const float*)d_in[12];
  const float* ln2_b    = (const float*)d_in[13];
  const float* W_out    = (const float*)d_in[14];
  const float* b_out    = (const float*)d_in[15];
  const int*   adj_rows = (const int*)d_in[16];
  const int*   adj_cols = (const int*)d_in[17];
  float* out = (float*)d_out;

  // workspace layout (bytes)
  char* wsb = (char*)d_ws;
  size_t off = 0;
  auto alloc = [&](size_t bytes) { void* p = wsb + off; off += (bytes + 255) & ~255ull; return p; };
  float* bn_sums = (float*)alloc(512 * 4);
  float* Wf      = (float*)alloc(35840 * 4);
  float* bf      = (float*)alloc(144 * 4);
  int*   rowptr  = (int*)alloc(100016 * 4);
  uint4* Bp1 = (uint4*)alloc(8 * 10 * 64 * 16);  // K=256: 8 ktiles, NT=10
  uint4* Bp2 = (uint4*)alloc(6 * 8 * 64 * 16);   // K=192: 6 ktiles, NT=8 (real K=140)
  uint4* Bp3 = (uint4*)alloc(4 * 7 * 64 * 16);   // K=128: 4 ktiles, NT=7
  uint4* Bp4 = (uint4*)alloc(4 * 4 * 64 * 16);   // K=128: 4 ktiles, NT=4
  unsigned short* h1  = (unsigned short*)alloc((size_t)N_NODES * 192 * 2);  // [N,192]; later LN outs [N,128]
  unsigned short* zb  = (unsigned short*)alloc((size_t)N_NODES * 128 * 2);  // hop buffers, 256B-aligned rows
  unsigned short* wb  = (unsigned short*)alloc((size_t)N_NODES * 128 * 2);
  unsigned short* lnb = h1;  // reuse: h1 dead after GEMM2

  hipMemsetAsync(bn_sums, 0, 512 * sizeof(float), stream);
  hipMemsetAsync(h1, 0, (size_t)N_NODES * 192 * 2, stream);  // cols 160..191 must be 0
  bn_stats_kernel<<<1024, 256, 0, stream>>>(x, bn_sums);
  fold_bn_kernel<<<140, 256, 0, stream>>>(bn_sums, bn_g, bn_b, W_in, b_in, Wf, bf);
  build_rowptr_kernel<<<(N_NODES + 256) / 256, 256, 0, stream>>>(adj_rows, rowptr);
  // pack weights
  pack_w_kernel<<<(8 * 10 * 64 + 255) / 256, 256, 0, stream>>>(Wf,    Bp1, 256, 140, 10, 8 * 10 * 64);
  pack_w_kernel<<<(6 * 8 * 64 + 255) / 256, 256, 0, stream>>>(W1,    Bp2, 140, 120, 8,  6 * 8 * 64);
  pack_w_kernel<<<(4 * 7 * 64 + 255) / 256, 256, 0, stream>>>(W2,    Bp3, 120, 100, 7,  4 * 7 * 64);
  pack_w_kernel<<<(4 * 4 * 64 + 255) / 256, 256, 0, stream>>>(W_out, Bp4, 100, 64,  4,  4 * 4 * 64);

  const int gemm_grid = (N_NODES + 127) / 128;  // 782
  const int spmm_grid = (N_NODES + 7) / 8;      // 12500
  const int ln_grid   = (N_NODES + 3) / 4;      // 25000

  // h1 = tanh(bn(x) @ Wf + bf)  [N,192] bf16; cols 140..159 zeroed here, 160..191 by memset
  mfma_gemm_kernel<8, 10, float><<<gemm_grid, 256, 0, stream>>>(
      x, Bp1, bf, h1, 140, 160, 192, 1, 1);
  // zb = h1 @ W1 (bias deferred)  [N,128] bf16, cols 120..127 zeroed (KPAD=192)
  mfma_gemm_kernel<6, 8, unsigned short><<<gemm_grid, 256, 0, stream>>>(
      h1, Bp2, nullptr, zb, 120, 128, 128, 0, 1);
  // 4 hops at F=120 (256B-aligned rows)
  spmm_bf16_kernel<120><<<spmm_grid, 256, 0, stream>>>(rowptr, adj_cols, adj_vals, zb, wb);
  spmm_bf16_kernel<120><<<spmm_grid, 256, 0, stream>>>(rowptr, adj_cols, adj_vals, wb, zb);
  spmm_bf16_kernel<120><<<spmm_grid, 256, 0, stream>>>(rowptr, adj_cols, adj_vals, zb, wb);
  spmm_bf16_kernel<120><<<spmm_grid, 256, 0, stream>>>(rowptr, adj_cols, adj_vals, wb, zb);
  // lnb = tanh(LN(zb + b1))  [N,128] bf16, cols 120..127 = 0
  bias_ln_tanh_kernel<120, 128, 128><<<ln_grid, 256, 0, stream>>>(zb, b1, ln1_g, ln1_b, lnb);
  // zb = lnb @ W2 (bias deferred)  [N,128-stride] bf16; cols 100..111 zeroed, 112..127 never read
  mfma_gemm_kernel<4, 7, unsigned short><<<gemm_grid, 256, 0, stream>>>(
      lnb, Bp3, nullptr, zb, 100, 112, 128, 0, 1);
  // 4 hops at F=100 (256B-aligned rows)
  spmm_bf16_kernel<100><<<spmm_grid, 256, 0, stream>>>(rowptr, adj_cols, adj_vals, zb, wb);
  spmm_bf16_kernel<100><<<spmm_grid, 256, 0, stream>>>(rowptr, adj_cols, adj_vals, wb, zb);
  spmm_bf16_kernel<100><<<spmm_grid, 256, 0, stream>>>(rowptr, adj_cols, adj_vals, zb, wb);
  spmm_bf16_kernel<100><<<spmm_grid, 256, 0, stream>>>(rowptr, adj_cols, adj_vals, wb, zb);
  // lnb = tanh(LN(zb + b2))  [N,128] bf16, cols 100..127 = 0
  bias_ln_tanh_kernel<100, 128, 128><<<ln_grid, 256, 0, stream>>>(zb, b2, ln2_g, ln2_b, lnb);
  // out = lnb @ W_out + b_out  [N,64] fp32
  mfma_gemm_kernel<4, 4, unsigned short><<<gemm_grid, 256, 0, stream>>>(
      lnb, Bp4, b_out, out, 64, 64, 64, 0, 0);
}

// Round 14
// 1342.026 us; speedup vs baseline: 1.3413x; 1.0016x over previous
//
#include <hip/hip_runtime.h>
#include <hip/hip_bf16.h>
#include <math.h>

#define N_NODES 100000
#define E_EDGES 3200000
#define IN_DIM  256

typedef __attribute__((ext_vector_type(8))) short bf16x8;
typedef __attribute__((ext_vector_type(4))) float f32x4;

// ---- bf16 helpers ---------------------------------------------------------
__device__ __forceinline__ unsigned short f2bf(float f) {
  unsigned u = __float_as_uint(f);
  u += 0x7fffu + ((u >> 16) & 1u);   // RTNE
  return (unsigned short)(u >> 16);
}
__device__ __forceinline__ float bf2f(unsigned short h) {
  return __uint_as_float(((unsigned)h) << 16);
}

// ---------------- BN column stats (sum, sumsq per feature) ----------------
__global__ __launch_bounds__(256) void bn_stats_kernel(
    const float* __restrict__ x, float* __restrict__ sums /*512 floats*/) {
  int c = threadIdx.x;
  float s = 0.f, s2 = 0.f;
  for (int r = blockIdx.x; r < N_NODES; r += gridDim.x) {
    float v = x[(size_t)r * IN_DIM + c];
    s += v; s2 += v * v;
  }
  atomicAdd(&sums[c], s);
  atomicAdd(&sums[256 + c], s2);
}

// ------------- fold BN affine into W_in / b_in ----------------------------
__global__ __launch_bounds__(256) void fold_bn_kernel(
    const float* __restrict__ sums, const float* __restrict__ bn_g,
    const float* __restrict__ bn_b, const float* __restrict__ W_in,
    const float* __restrict__ b_in, float* __restrict__ Wf,
    float* __restrict__ bf) {
  int j = blockIdx.x;   // out col 0..139
  int c = threadIdx.x;  // in col 0..255
  const float invN = 1.0f / (float)N_NODES;
  float mu  = sums[c] * invN;
  float var = sums[256 + c] * invN - mu * mu;
  float s   = bn_g[c] * rsqrtf(var + 1e-5f);
  float t   = bn_b[c] - mu * s;
  float w   = W_in[(size_t)c * 140 + j];
  Wf[(size_t)c * 140 + j] = s * w;
  float v = t * w;
  for (int o = 32; o > 0; o >>= 1) v += __shfl_down(v, o, 64);
  __shared__ float red[4];
  int wid = threadIdx.x >> 6, lane = threadIdx.x & 63;
  if (lane == 0) red[wid] = v;
  __syncthreads();
  if (threadIdx.x == 0)
    bf[j] = b_in[j] + red[0] + red[1] + red[2] + red[3];
}

// ---------------- CSR row_ptr from sorted rows (binary search) -------------
__global__ __launch_bounds__(256) void build_rowptr_kernel(
    const int* __restrict__ rows, int* __restrict__ rowptr) {
  int r = blockIdx.x * 256 + threadIdx.x;
  if (r > N_NODES) return;
  int lo = 0, hi = E_EDGES;
  while (lo < hi) {
    int mid = (lo + hi) >> 1;
    if (rows[mid] < r) lo = mid + 1; else hi = mid;
  }
  rowptr[r] = lo;
}

// ------- pack fp32 W[K,M] into MFMA B-fragment order, bf16, zero-padded ----
// Bp[(kt*NT + nt)*64 + lane] = uint4 of 8 bf16: B[kt*32+(lane>>4)*8+j][nt*16+(lane&15)]
__global__ __launch_bounds__(256) void pack_w_kernel(
    const float* __restrict__ W, uint4* __restrict__ Bp, int K, int M, int NT,
    int total) {
  int id = blockIdx.x * 256 + threadIdx.x;
  if (id >= total) return;
  int lane = id & 63;
  int nt = (id >> 6) % NT;
  int kt = id / (64 * NT);
  int n = nt * 16 + (lane & 15);
  int kbase = kt * 32 + (lane >> 4) * 8;
  unsigned short v[8];
#pragma unroll
  for (int j = 0; j < 8; ++j) {
    int k = kbase + j;
    v[j] = (k < K && n < M) ? f2bf(W[(size_t)k * M + n]) : (unsigned short)0;
  }
  Bp[id] = *(uint4*)v;
}

// ---------------- MFMA bf16 GEMM (barrier-free, no LDS) --------------------
// MEASURED GOOD (r10): all GEMMs left the top-5 (<107us; was 147us staged).
// Direct-from-global A fragments, L2-resident packed B, no LDS/barriers.
template <int KT, int NT, typename AT>
__global__ __launch_bounds__(256) void mfma_gemm_kernel(
    const AT* __restrict__ A, const uint4* __restrict__ Bp,
    const float* __restrict__ bias, void* __restrict__ C,
    int M, int Mstore, int ldc, int act, int outfmt) {
  constexpr int KPAD = KT * 32;
  int tid = threadIdx.x;
  int lane = tid & 63;
  int wave = tid >> 6;
  int quad = lane >> 4, m16 = lane & 15;
  int rbase = blockIdx.x * 128 + wave * 32;  // this wave's 32 output rows
  int row0 = rbase + m16;
  int row1 = rbase + 16 + m16;
  bool ok0 = row0 < N_NODES, ok1 = row1 < N_NODES;

  f32x4 acc[2][NT];
#pragma unroll
  for (int mt = 0; mt < 2; ++mt)
#pragma unroll
    for (int nt = 0; nt < NT; ++nt)
      acc[mt][nt] = (f32x4){0.f, 0.f, 0.f, 0.f};

#pragma unroll 2
  for (int kt = 0; kt < KT; ++kt) {
    int k0 = kt * 32;
    bf16x8 a0, a1;
    if constexpr (sizeof(AT) == 2) {
      uint4 v0 = make_uint4(0u, 0u, 0u, 0u), v1 = v0;
      if (ok0) v0 = *(const uint4*)((const unsigned short*)A + (size_t)row0 * KPAD + k0 + quad * 8);
      if (ok1) v1 = *(const uint4*)((const unsigned short*)A + (size_t)row1 * KPAD + k0 + quad * 8);
      a0 = *(const bf16x8*)&v0;
      a1 = *(const bf16x8*)&v1;
    } else {
      float4 p0 = make_float4(0.f, 0.f, 0.f, 0.f), p1 = p0, q0 = p0, q1 = p0;
      if (ok0) {
        p0 = *(const float4*)((const float*)A + (size_t)row0 * KPAD + k0 + quad * 8);
        q0 = *(const float4*)((const float*)A + (size_t)row0 * KPAD + k0 + quad * 8 + 4);
      }
      if (ok1) {
        p1 = *(const float4*)((const float*)A + (size_t)row1 * KPAD + k0 + quad * 8);
        q1 = *(const float4*)((const float*)A + (size_t)row1 * KPAD + k0 + quad * 8 + 4);
      }
      unsigned short w0[8] = {f2bf(p0.x), f2bf(p0.y), f2bf(p0.z), f2bf(p0.w),
                              f2bf(q0.x), f2bf(q0.y), f2bf(q0.z), f2bf(q0.w)};
      unsigned short w1[8] = {f2bf(p1.x), f2bf(p1.y), f2bf(p1.z), f2bf(p1.w),
                              f2bf(q1.x), f2bf(q1.y), f2bf(q1.z), f2bf(q1.w)};
      a0 = *(const bf16x8*)w0;
      a1 = *(const bf16x8*)w1;
    }
    const uint4* bp = Bp + (size_t)(kt * NT) * 64 + lane;
#pragma unroll
    for (int nt = 0; nt < NT; ++nt) {
      uint4 bw = bp[(size_t)nt * 64];
      bf16x8 b = *(const bf16x8*)&bw;
      acc[0][nt] = __builtin_amdgcn_mfma_f32_16x16x32_bf16(a0, b, acc[0][nt], 0, 0, 0);
      acc[1][nt] = __builtin_amdgcn_mfma_f32_16x16x32_bf16(a1, b, acc[1][nt], 0, 0, 0);
    }
  }

  // epilogue: C/D layout col=lane&15, row=quad*4+reg
#pragma unroll
  for (int mt = 0; mt < 2; ++mt)
#pragma unroll
    for (int nt = 0; nt < NT; ++nt)
#pragma unroll
      for (int i = 0; i < 4; ++i) {
        int row = rbase + mt * 16 + quad * 4 + i;
        int col = nt * 16 + m16;
        if (row >= N_NODES || col >= Mstore) continue;
        float c = acc[mt][nt][i];
        if (col < M) {
          if (bias) c += bias[col];
          if (act) c = tanhf(c);
        } else {
          c = 0.f;  // zero pad for downstream K-padding
        }
        if (outfmt == 0)
          ((float*)C)[(size_t)row * ldc + col] = c;
        else
          ((unsigned short*)C)[(size_t)row * ldc + col] = f2bf(c);
      }
}

// ---------------- SPMM (bf16 in/out, fp32 accum) ---------------------------
// r10 measured: 107us/hop, VALUBusy 31%, Occ 64%, FETCH 361MB (3.7 TB/s
// fabric). VGPR=36 proved NO cross-group pipelining: 8-load groups serialize
// at group boundaries. Unmeasured fix (resubmitted): 2-buffer software
// pipeline — group g+1's gathers (and the next 32-edge block's cols/vals +
// group0) issue WHILE group g's FMAs run. v-values re-shuffled at use to
// stay under the 64-VGPR occupancy cliff. DOLN fuses bias+LayerNorm+tanh
// into the last hop of each group (row register-resident; 32-lane reduce).
#define BLO(u) __uint_as_float((u) << 16)
#define BHI(u) __uint_as_float((u) & 0xffff0000u)
#define ISSUE8(buf, base, CL) { \
  _Pragma("unroll") for (int jj = 0; jj < 8; ++jj) { \
    int cc = __shfl((CL), (base) + jj, 32); \
    buf[jj] = xin2[(size_t)cc * LDQ + myoff]; } }
#define FMA8(buf, base, VL) { \
  _Pragma("unroll") for (int jj = 0; jj < 8; ++jj) { \
    float vv = __shfl((VL), (base) + jj, 32); \
    acc.x = fmaf(vv, BLO(buf[jj].x), acc.x); \
    acc.y = fmaf(vv, BHI(buf[jj].x), acc.y); \
    acc.z = fmaf(vv, BLO(buf[jj].y), acc.z); \
    acc.w = fmaf(vv, BHI(buf[jj].y), acc.w); } }

template <int F, int DOLN>
__global__ __launch_bounds__(256) void spmm_bf16_kernel(
    const int* __restrict__ rowptr, const int* __restrict__ cols,
    const float* __restrict__ vals, const unsigned short* __restrict__ xin,
    unsigned short* __restrict__ xout, const float* __restrict__ bias,
    const float* __restrict__ lng, const float* __restrict__ lnbb) {
  constexpr int FQ = F / 4;      // uint2 (4 bf16) chunks of real data per row
  constexpr int LDQ = 32;        // row stride in uint2 = 128 bf16 = 256B
  int lane = threadIdx.x & 31;
  int r = blockIdx.x * 8 + (threadIdx.x >> 5);
  if (r >= N_NODES) return;
  int e0 = rowptr[r], e1 = rowptr[r + 1];
  int myoff = (lane < FQ) ? lane : 0;
  const uint2* xin2 = (const uint2*)xin;

  float4 acc = make_float4(0.f, 0.f, 0.f, 0.f);
  uint2 uA[8], uB[8];

  int eb = e0;
  int n = e1 - eb; if (n > 32) n = 32; if (n < 0) n = 0;
  int c_l = 0; float v_l = 0.f;
  if (eb < e1 && lane < n) {
    c_l = __builtin_nontemporal_load(cols + eb + lane);
    v_l = __builtin_nontemporal_load(vals + eb + lane);
  }
  if (eb < e1) ISSUE8(uA, 0, c_l)   // prologue: group0 of first block

  while (eb < e1) {
    int ebn = eb + 32;
    int nn = e1 - ebn; if (nn > 32) nn = 32; if (nn < 0) nn = 0;
    int c_n = 0; float v_n = 0.f;
    if (nn > 0 && lane < nn) {
      c_n = __builtin_nontemporal_load(cols + ebn + lane);
      v_n = __builtin_nontemporal_load(vals + ebn + lane);
    }

    if (8 < n)  ISSUE8(uB, 8, c_l)      // overlap: issue g1 before g0 FMAs
    FMA8(uA, 0, v_l)                    // n>=1 inside loop
    if (16 < n) ISSUE8(uA, 16, c_l)     // g2 into freed uA
    if (8 < n)  FMA8(uB, 8, v_l)
    if (24 < n) ISSUE8(uB, 24, c_l)     // g3 into freed uB
    if (16 < n) FMA8(uA, 16, v_l)
    if (nn > 0) ISSUE8(uA, 0, c_n)      // next block's g0 into freed uA
    if (24 < n) FMA8(uB, 24, v_l)

    eb = ebn; n = nn; c_l = c_n; v_l = v_n;
  }

  if (DOLN) {
    // fused bias + LayerNorm + tanh over this row's F features
    bool al = lane < FQ;
    int cb = lane * 4;
    float x0 = 0.f, x1 = 0.f, x2 = 0.f, x3 = 0.f;
    if (al) {
      x0 = acc.x + bias[cb];     x1 = acc.y + bias[cb + 1];
      x2 = acc.z + bias[cb + 2]; x3 = acc.w + bias[cb + 3];
    }
    float s  = x0 + x1 + x2 + x3;
    float s2 = x0 * x0 + x1 * x1 + x2 * x2 + x3 * x3;
    for (int o = 16; o > 0; o >>= 1) {
      s  += __shfl_xor(s, o, 32);
      s2 += __shfl_xor(s2, o, 32);
    }
    const float invF = 1.0f / (float)F;
    float mu = s * invF;
    float var = s2 * invF - mu * mu;
    float rs = rsqrtf(var + 1e-5f);
    uint2 o2; o2.x = 0u; o2.y = 0u;
    if (al) {
      float y0 = tanhf((x0 - mu) * rs * lng[cb]     + lnbb[cb]);
      float y1 = tanhf((x1 - mu) * rs * lng[cb + 1] + lnbb[cb + 1]);
      float y2 = tanhf((x2 - mu) * rs * lng[cb + 2] + lnbb[cb + 2]);
      float y3 = tanhf((x3 - mu) * rs * lng[cb + 3] + lnbb[cb + 3]);
      o2.x = (unsigned)f2bf(y0) | ((unsigned)f2bf(y1) << 16);
      o2.y = (unsigned)f2bf(y2) | ((unsigned)f2bf(y3) << 16);
    }
    ((uint2*)xout)[(size_t)r * LDQ + lane] = o2;  // all 32 lanes: pads zeroed
  } else {
    if (lane < FQ) {
      uint2 o;
      o.x = (unsigned)f2bf(acc.x) | ((unsigned)f2bf(acc.y) << 16);
      o.y = (unsigned)f2bf(acc.z) | ((unsigned)f2bf(acc.w) << 16);
      ((uint2*)xout)[(size_t)r * LDQ + lane] = o;
    }
  }
}

// ---------------------------------------------------------------------------
extern "C" void kernel_launch(void* const* d_in, const int* in_sizes, int n_in,
                              void* d_out, int out_size, void* d_ws,
                              size_t ws_size, hipStream_t stream) {
  const float* x        = (const float*)d_in[0];
  const float* adj_vals = (const float*)d_in[1];
  const float* bn_g     = (const float*)d_in[2];
  const float* bn_b     = (const float*)d_in[3];
  const float* W_in     = (const float*)d_in[4];
  const float* b_in     = (const float*)d_in[5];
  const float* W1       = (const float*)d_in[6];
  const float* b1       = (const float*)d_in[7];
  const float* ln1_g    = (const float*)d_in[8];
  const float* ln1_b    = (const float*)d_in[9];
  const float* W2       = (const float*)d_in[10];
  const float* b2       = (const float*)d_in[11];
  const float* ln2_g    = (const float*)d_in[12];
  const float* ln2_b    = (const float*)d_in[13];
  const float* W_out    = (const float*)d_in[14];
  const float* b_out    = (const float*)d_in[15];
  const int*   adj_rows = (const int*)d_in[16];
  const int*   adj_cols = (const int*)d_in[17];
  float* out = (float*)d_out;

  // workspace layout (bytes)
  char* wsb = (char*)d_ws;
  size_t off = 0;
  auto alloc = [&](size_t bytes) { void* p = wsb + off; off += (bytes + 255) & ~255ull; return p; };
  float* bn_sums = (float*)alloc(512 * 4);
  float* Wf      = (float*)alloc(35840 * 4);
  float* bf      = (float*)alloc(144 * 4);
  int*   rowptr  = (int*)alloc(100016 * 4);
  uint4* Bp1 = (uint4*)alloc(8 * 10 * 64 * 16);  // K=256: 8 ktiles, NT=10
  uint4* Bp2 = (uint4*)alloc(6 * 8 * 64 * 16);   // K=192: 6 ktiles, NT=8 (real K=140)
  uint4* Bp3 = (uint4*)alloc(4 * 7 * 64 * 16);   // K=128: 4 ktiles, NT=7
  uint4* Bp4 = (uint4*)alloc(4 * 4 * 64 * 16);   // K=128: 4 ktiles, NT=4
  unsigned short* h1  = (unsigned short*)alloc((size_t)N_NODES * 192 * 2);  // [N,192]; later LN outs [N,128]
  unsigned short* zb  = (unsigned short*)alloc((size_t)N_NODES * 128 * 2);  // hop buffers, 256B-aligned rows
  unsigned short* wb  = (unsigned short*)alloc((size_t)N_NODES * 128 * 2);
  unsigned short* lnb = h1;  // reuse: h1 dead after GEMM2

  hipMemsetAsync(bn_sums, 0, 512 * sizeof(float), stream);
  hipMemsetAsync(h1, 0, (size_t)N_NODES * 192 * 2, stream);  // cols 160..191 must be 0
  bn_stats_kernel<<<1024, 256, 0, stream>>>(x, bn_sums);
  fold_bn_kernel<<<140, 256, 0, stream>>>(bn_sums, bn_g, bn_b, W_in, b_in, Wf, bf);
  build_rowptr_kernel<<<(N_NODES + 256) / 256, 256, 0, stream>>>(adj_rows, rowptr);
  // pack weights
  pack_w_kernel<<<(8 * 10 * 64 + 255) / 256, 256, 0, stream>>>(Wf,    Bp1, 256, 140, 10, 8 * 10 * 64);
  pack_w_kernel<<<(6 * 8 * 64 + 255) / 256, 256, 0, stream>>>(W1,    Bp2, 140, 120, 8,  6 * 8 * 64);
  pack_w_kernel<<<(4 * 7 * 64 + 255) / 256, 256, 0, stream>>>(W2,    Bp3, 120, 100, 7,  4 * 7 * 64);
  pack_w_kernel<<<(4 * 4 * 64 + 255) / 256, 256, 0, stream>>>(W_out, Bp4, 100, 64,  4,  4 * 4 * 64);

  const int gemm_grid = (N_NODES + 127) / 128;  // 782
  const int spmm_grid = (N_NODES + 7) / 8;      // 12500

  // h1 = tanh(bn(x) @ Wf + bf)  [N,192] bf16; cols 140..159 zeroed here, 160..191 by memset
  mfma_gemm_kernel<8, 10, float><<<gemm_grid, 256, 0, stream>>>(
      x, Bp1, bf, h1, 140, 160, 192, 1, 1);
  // zb = h1 @ W1 (bias deferred)  [N,128] bf16, cols 120..127 zeroed (KPAD=192)
  mfma_gemm_kernel<6, 8, unsigned short><<<gemm_grid, 256, 0, stream>>>(
      h1, Bp2, nullptr, zb, 120, 128, 128, 0, 1);
  // 4 hops at F=120; hop 4 fuses bias+LN+tanh -> lnb
  spmm_bf16_kernel<120, 0><<<spmm_grid, 256, 0, stream>>>(rowptr, adj_cols, adj_vals, zb, wb, nullptr, nullptr, nullptr);
  spmm_bf16_kernel<120, 0><<<spmm_grid, 256, 0, stream>>>(rowptr, adj_cols, adj_vals, wb, zb, nullptr, nullptr, nullptr);
  spmm_bf16_kernel<120, 0><<<spmm_grid, 256, 0, stream>>>(rowptr, adj_cols, adj_vals, zb, wb, nullptr, nullptr, nullptr);
  spmm_bf16_kernel<120, 1><<<spmm_grid, 256, 0, stream>>>(rowptr, adj_cols, adj_vals, wb, lnb, b1, ln1_g, ln1_b);
  // zb = lnb @ W2 (bias deferred)  [N,128-stride] bf16; cols 100..111 zeroed, 112..127 never read
  mfma_gemm_kernel<4, 7, unsigned short><<<gemm_grid, 256, 0, stream>>>(
      lnb, Bp3, nullptr, zb, 100, 112, 128, 0, 1);
  // 4 hops at F=100; hop 8 fuses bias+LN+tanh -> lnb
  spmm_bf16_kernel<100, 0><<<spmm_grid, 256, 0, stream>>>(rowptr, adj_cols, adj_vals, zb, wb, nullptr, nullptr, nullptr);
  spmm_bf16_kernel<100, 0><<<spmm_grid, 256, 0, stream>>>(rowptr, adj_cols, adj_vals, wb, zb, nullptr, nullptr, nullptr);
  spmm_bf16_kernel<100, 0><<<spmm_grid, 256, 0, stream>>>(rowptr, adj_cols, adj_vals, zb, wb, nullptr, nullptr, nullptr);
  spmm_bf16_kernel<100, 1><<<spmm_grid, 256, 0, stream>>>(rowptr, adj_cols, adj_vals, wb, lnb, b2, ln2_g, ln2_b);
  // out = lnb @ W_out + b_out  [N,64] fp32
  mfma_gemm_kernel<4, 4, unsigned short><<<gemm_grid, 256, 0, stream>>>(
      lnb, Bp4, b_out, out, 64, 64, 64, 0, 0);
}